// Round 1
// 768.025 us; speedup vs baseline: 1.1066x; 1.1066x over previous
//
#include <hip/hip_runtime.h>

typedef unsigned short u16;
typedef unsigned int u32;
typedef u16 u16x8 __attribute__((ext_vector_type(8)));
typedef __bf16 bf16x8 __attribute__((ext_vector_type(8)));
typedef float f32x4 __attribute__((ext_vector_type(4)));

#define TOKENS 4096
#define DMODEL 4096
#define QKVN 6144
#define NHEAD 32
#define NKV 8
#define DHEAD 128
#define SEQ 2048

#define BARRIER() asm volatile("s_barrier" ::: "memory")
#define LGKM0() asm volatile("s_waitcnt lgkmcnt(0)" ::: "memory")
#define VMCNT(n) asm volatile("s_waitcnt vmcnt(" #n ")" ::: "memory")

__device__ inline u16 f2bf(float f) {
    unsigned int u = __float_as_uint(f);
    u += 0x7fffu + ((u >> 16) & 1u);
    return (u16)(u >> 16);
}
__device__ inline float bf2f(u16 h) {
    return __uint_as_float(((unsigned int)h) << 16);
}
__device__ inline u32 pack2bf(float a, float b) {
    return (u32)f2bf(a) | ((u32)f2bf(b) << 16);
}
__device__ inline f32x4 mfma16(bf16x8 a, bf16x8 b, f32x4 c) {
    return __builtin_amdgcn_mfma_f32_16x16x32_bf16(a, b, c, 0, 0, 0);
}
__device__ __forceinline__ void gload16(const u16* g, u16* l) {
    __builtin_amdgcn_global_load_lds((const __attribute__((address_space(1))) u32*)g,
                                     (__attribute__((address_space(3))) u32*)l, 16, 0, 0);
}

// ---------------- fp32 -> bf16 convert ----------------
__global__ __launch_bounds__(256) void f2bf_kernel(const float* __restrict__ in,
                                                   u16* __restrict__ out, int n) {
    int i = (blockIdx.x * 256 + threadIdx.x) * 4;
    if (i >= n) return;
    float4 v = *(const float4*)(in + i);
    u16 o0 = f2bf(v.x), o1 = f2bf(v.y), o2 = f2bf(v.z), o3 = f2bf(v.w);
    u16* p = out + i;
    p[0] = o0; p[1] = o1; p[2] = o2; p[3] = o3;
}

// ---------------- transpose + convert: w[K][N] fp32 -> wt[N][K] bf16 ----------------
__global__ __launch_bounds__(256) void transpose_kernel(const float* __restrict__ in,
                                                        u16* __restrict__ out,
                                                        int K, int N) {
    __shared__ float t[32][33];
    int n0 = blockIdx.x * 32, k0 = blockIdx.y * 32;
    int x = threadIdx.x, y = threadIdx.y;
#pragma unroll
    for (int i = 0; i < 4; i++)
        t[y + 8 * i][x] = in[(size_t)(k0 + y + 8 * i) * N + n0 + x];
    __syncthreads();
#pragma unroll
    for (int i = 0; i < 4; i++)
        out[(size_t)(n0 + y + 8 * i) * K + k0 + x] = f2bf(t[x][y + 8 * i]);
}

// ---------------- bf16 transpose for V: qkv cols [5120..6144) -> vt[b][dcol][seq] ----
__global__ __launch_bounds__(256) void vtrans_kernel(const u16* __restrict__ qkv,
                                                     u16* __restrict__ vt) {
    __shared__ u16 t[32][33];
    int b = blockIdx.z;
    int c0 = blockIdx.x * 32;  // dcol (kvh*128+d), 0..1023
    int r0 = blockIdx.y * 32;  // tok within seq, 0..2047
    int x = threadIdx.x, y = threadIdx.y;
    const u16* in = qkv + (size_t)(b * SEQ) * QKVN + 5120;
#pragma unroll
    for (int i = 0; i < 4; i++)
        t[y + 8 * i][x] = in[(size_t)(r0 + y + 8 * i) * QKVN + c0 + x];
    __syncthreads();
    u16* out = vt + (size_t)b * 1024 * SEQ;
#pragma unroll
    for (int i = 0; i < 4; i++)
        out[(size_t)(c0 + y + 8 * i) * SEQ + r0 + x] = t[x][y + 8 * i];
}

// ---------------- GEMM: 256x256 8-phase template (T2+T3+T4+T5) ----------------
// C[M][N] = A[M][K] * Bt[N][K]^T. 512 thr = 8 waves (2M x 4N), per-wave 128x64 out.
// LDS 128 KiB: [op][dbuf][half][128][64] bf16, XOR-swizzled 16B slots
// (byte ^= (row&7)<<4) applied via pre-swizzled global source (gload_lds is linear).
// Counted vmcnt(6): 3 half-tiles always in flight; main loop never drains.
template <bool OUT_F32>
__global__ __launch_bounds__(512, 2) void gemm256(const u16* __restrict__ A,
                                                  const u16* __restrict__ Bt,
                                                  void* __restrict__ C,
                                                  int M, int N, int K) {
    __shared__ u16 lds[2][2][2][128 * 64];  // [A0/B1][buf][half][row*64+k]
    const int tid = threadIdx.x, wave = tid >> 6, lane = tid & 63;
    const int quad = lane >> 4, l16 = lane & 15;
    const int wave_m = wave >> 2, wave_n = wave & 3;
    const int m0 = blockIdx.y * 256, n0 = blockIdx.x * 256;
    const int wn = wave_n * 64;
    const int nk = K >> 6;

    // staging: wave w covers rows w*16..w*16+15 of each 128-row half (2 x gload16).
    // global col pre-swizzle: lane l loads k-slot (l&7)^(l>>3) so swizzled read matches.
    const int srow = wave * 16 + (lane >> 3);
    const int scol = ((lane & 7) ^ (lane >> 3)) << 3;
    const u16* ga0 = A + (size_t)(m0 + srow) * K + scol;
    const u16* gb0 = Bt + (size_t)(n0 + srow) * K + scol;

    auto STAGE = [&](int op, int buf, int half, int kt) {
        const u16* src = (op ? gb0 : ga0) + (size_t)(half * 128) * K + (kt << 6);
        u16* dst = &lds[op][buf][half][wave * 1024];
        gload16(src, dst);
        gload16(src + (size_t)8 * K, dst + 512);
    };
    auto FRAG = [&](const u16* base, int lr, int c) -> bf16x8 {
        int idx = (lr * 64 + c) ^ ((lr & 7) << 3);  // swizzled read
        return *(const bf16x8*)(base + idx);
    };

    f32x4 acc[8][4] = {};

    // prologue: stream {K0:B0,B1,A0,A1, K1:B0,B1,A0}; retire K0, keep 3 in flight
    STAGE(1, 0, 0, 0); STAGE(1, 0, 1, 0); STAGE(0, 0, 0, 0); STAGE(0, 0, 1, 0);
    STAGE(1, 1, 0, 1); STAGE(1, 1, 1, 1); STAGE(0, 1, 0, 1);
    VMCNT(6);
    BARRIER();

    bf16x8 af[4][2], bfr[4][2];

    auto KTILE = [&](int kt, int cur) {
        const int nxt = cur ^ 1;
        const int k1 = kt + 1 < nk ? kt + 1 : nk - 1;  // clamped tail stages land in
        const int k2 = kt + 2 < nk ? kt + 2 : nk - 1;  // dead buffers (never read)
        const u16* aB = &lds[0][cur][wave_m][0];
        // ===== phase 1: quadrant (M0,N0); read A-M0 (8) + all B (8) =====
#pragma unroll
        for (int i = 0; i < 4; i++)
#pragma unroll
            for (int kk = 0; kk < 2; kk++)
                af[i][kk] = FRAG(aB, i * 16 + l16, kk * 32 + quad * 8);
#pragma unroll
        for (int j = 0; j < 4; j++) {
            const int brow = wn + j * 16;
            const u16* bB = &lds[1][cur][brow >> 7][0];
#pragma unroll
            for (int kk = 0; kk < 2; kk++)
                bfr[j][kk] = FRAG(bB, (brow & 127) + l16, kk * 32 + quad * 8);
        }
        STAGE(0, nxt, 1, k1);  // K_{kt+1}:A1 (its A-half reads ended last K-tile)
        BARRIER();
        __builtin_amdgcn_s_setprio(1);
#pragma unroll
        for (int i = 0; i < 4; i++)
#pragma unroll
            for (int j = 0; j < 2; j++)
#pragma unroll
                for (int kk = 0; kk < 2; kk++)
                    acc[i][j] = mfma16(af[i][kk], bfr[j][kk], acc[i][j]);
        __builtin_amdgcn_s_setprio(0);
        LGKM0();  // all ph1 ds_reads (incl. bfr[2..3]) landed before B0 overwrite
        BARRIER();
        // ===== phase 2: quadrant (M0,N1); no reads =====
        STAGE(1, cur, 0, k2);  // K_{kt+2}:B0 (all B reads of cur done in ph1)
        BARRIER();
        __builtin_amdgcn_s_setprio(1);
#pragma unroll
        for (int i = 0; i < 4; i++)
#pragma unroll
            for (int j = 0; j < 2; j++)
#pragma unroll
                for (int kk = 0; kk < 2; kk++)
                    acc[i][2 + j] = mfma16(af[i][kk], bfr[2 + j][kk], acc[i][2 + j]);
        __builtin_amdgcn_s_setprio(0);
        BARRIER();
        // ===== phase 3: quadrant (M1,N0); read A-M1 (8) =====
#pragma unroll
        for (int i = 0; i < 4; i++)
#pragma unroll
            for (int kk = 0; kk < 2; kk++)
                af[i][kk] = FRAG(aB, 64 + i * 16 + l16, kk * 32 + quad * 8);
        STAGE(1, cur, 1, k2);  // K_{kt+2}:B1
        BARRIER();
        __builtin_amdgcn_s_setprio(1);
#pragma unroll
        for (int i = 0; i < 4; i++)
#pragma unroll
            for (int j = 0; j < 2; j++)
#pragma unroll
                for (int kk = 0; kk < 2; kk++)
                    acc[4 + i][j] = mfma16(af[i][kk], bfr[j][kk], acc[4 + i][j]);
        __builtin_amdgcn_s_setprio(0);
        LGKM0();  // A-M1 reads landed before ph4's A0 overwrite
        BARRIER();
        // ===== phase 4: quadrant (M1,N1); no reads; K-tile fence =====
        STAGE(0, cur, 0, k2);  // K_{kt+2}:A0
        BARRIER();
        __builtin_amdgcn_s_setprio(1);
#pragma unroll
        for (int i = 0; i < 4; i++)
#pragma unroll
            for (int j = 0; j < 2; j++)
#pragma unroll
                for (int kk = 0; kk < 2; kk++)
                    acc[4 + i][2 + j] = mfma16(af[i][kk], bfr[2 + j][kk], acc[4 + i][2 + j]);
        __builtin_amdgcn_s_setprio(0);
        VMCNT(6);  // retires through K_{kt+1}:A1; leaves 3 half-tiles in flight
        BARRIER();
    };

    for (int kt = 0; kt < nk; kt += 2) {
        KTILE(kt, 0);
        KTILE(kt + 1, 1);
    }

    VMCNT(0);  // drain tail stages before endpgm

    // epilogue: C write (layout: row = quad*4+r, col = l16 — verified convention)
#pragma unroll
    for (int i = 0; i < 8; i++)
#pragma unroll
        for (int j = 0; j < 4; j++) {
            const int row = m0 + wave_m * 128 + i * 16 + quad * 4;
            const int col = n0 + wn + j * 16 + l16;
            if (OUT_F32) {
                float* Cf = (float*)C;
#pragma unroll
                for (int r = 0; r < 4; r++)
                    Cf[(size_t)(row + r) * N + col] = acc[i][j][r];
            } else {
                u16* Cb = (u16*)C;
#pragma unroll
                for (int r = 0; r < 4; r++)
                    Cb[(size_t)(row + r) * N + col] = f2bf(acc[i][j][r]);
            }
        }
}

// ---------------- RoPE on fused qkv buffer (packed u32, optional scale fold) --------
__global__ __launch_bounds__(256) void rope2_kernel(u16* __restrict__ buf,
                                                    const float* __restrict__ cosb,
                                                    const float* __restrict__ sinb,
                                                    int nheads, int colbase, float scale) {
    int idx = blockIdx.x * 256 + threadIdx.x;
    int p = idx & 63;
    int rest = idx >> 6;
    int h = rest & (nheads - 1);
    int tok = rest / nheads;
    int tseq = tok & (SEQ - 1);
    float c = cosb[tseq * 64 + p], s = sinb[tseq * 64 + p];
    u32* ptr = (u32*)(buf + (size_t)tok * QKVN + colbase + h * DHEAD + 2 * p);
    u32 v = *ptr;
    float xr = bf2f((u16)(v & 0xffff)), xi = bf2f((u16)(v >> 16));
    float orr = (xr * c - xi * s) * scale;
    float oii = (xr * s + xi * c) * scale;
    *ptr = pack2bf(orr, oii);
}

// ---------------- Flash attention v2 ----------------
// grid (16, 32, 2) = (qtile, head, b), 256 thr = 4 waves. Q-tile 128 (32 q/wave),
// 64-key tiles. S^T = K*Q^T (K natural A-operand), V pre-transposed globally.
// LDS: K [kk][key][32], Vt [kf][d][32] (global_load_lds, m97 pattern), P padded.
#define LDP 72
#define NINF (-__builtin_inff())

__global__ __launch_bounds__(256, 2) void flash2_kernel(const u16* __restrict__ QKV,
                                                        const u16* __restrict__ Vt,
                                                        u16* __restrict__ Z) {
    __shared__ u16 lK[4][64 * 32];
    __shared__ u16 lV[2][128 * 32];
    __shared__ u16 lP[4][32 * LDP];
    int tid = threadIdx.x, wave = tid >> 6, lane = tid & 63;
    int quad = lane >> 4, l16 = lane & 15;
    int qt = 15 - (int)blockIdx.x;  // big tiles first
    int h = blockIdx.y, b = blockIdx.z;
    int kvh = h >> 2;
    int Q0 = qt * 128;
    int qw = Q0 + wave * 32;
    int lrow = lane >> 2, lcol = (lane & 3) * 8;

    // Q fragments (1/sqrt(128) pre-folded by rope)
    bf16x8 qf[2][4];
#pragma unroll
    for (int nt = 0; nt < 2; nt++) {
        const u16* qp = QKV + (size_t)(b * SEQ + qw + nt * 16 + l16) * QKVN + h * DHEAD;
#pragma unroll
        for (int kk = 0; kk < 4; kk++)
            qf[nt][kk] = *(const bf16x8*)(qp + kk * 32 + quad * 8);
    }

    f32x4 o[2][8] = {};
    float mrun[2] = {NINF, NINF};
    float lrun[2] = {0.f, 0.f};

    // staging bases
    const u16* gk = QKV + (size_t)(b * SEQ + lrow) * QKVN + DMODEL + kvh * DHEAD + wave * 32 + lcol;
    u16* lk = lK[wave];
    int kf_w = wave >> 1, dh_w = (wave & 1) * 64;
    const u16* gv = Vt + ((size_t)(b * NKV + kvh) * DHEAD + dh_w + lrow) * SEQ + kf_w * 32 + lcol;
    u16* lv = lV[kf_w] + dh_w * 32;

    int nkt = 2 * qt + 2;
    for (int kt = 0; kt < nkt; kt++) {
        int key0 = kt * 64;
        if (kt) __syncthreads();  // prev tile's reads done
#pragma unroll
        for (int g = 0; g < 4; g++)
            gload16(gk + (size_t)(key0 + g * 16) * QKVN, lk + g * 512);
#pragma unroll
        for (int g = 0; g < 4; g++)
            gload16(gv + (size_t)(g * 16) * SEQ + key0, lv + g * 512);
        __syncthreads();  // staged tile ready (vmcnt drained)

        if (key0 <= qw + 31) {
            // S^T: m=key (4 tiles), n=q (2 tiles)
            f32x4 st[4][2] = {};
#pragma unroll
            for (int kk = 0; kk < 4; kk++) {
                bf16x8 kfr[4];
#pragma unroll
                for (int mt = 0; mt < 4; mt++)
                    kfr[mt] = *(const bf16x8*)(lK[kk] + (mt * 16 + l16) * 32 + quad * 8);
#pragma unroll
                for (int mt = 0; mt < 4; mt++)
#pragma unroll
                    for (int nt = 0; nt < 2; nt++)
                        st[mt][nt] = mfma16(kfr[mt], qf[nt][kk], st[mt][nt]);
            }
            if (key0 + 63 > qw) {  // causal mask needed
#pragma unroll
                for (int mt = 0; mt < 4; mt++)
#pragma unroll
                    for (int nt = 0; nt < 2; nt++)
#pragma unroll
                        for (int r = 0; r < 4; r++)
                            if (key0 + mt * 16 + quad * 4 + r > qw + nt * 16 + l16)
                                st[mt][nt][r] = NINF;
            }
            float alpha[2];
#pragma unroll
            for (int nt = 0; nt < 2; nt++) {
                float vmax = NINF;
#pragma unroll
                for (int mt = 0; mt < 4; mt++)
#pragma unroll
                    for (int r = 0; r < 4; r++) vmax = fmaxf(vmax, st[mt][nt][r]);
                vmax = fmaxf(vmax, __shfl_xor(vmax, 16));
                vmax = fmaxf(vmax, __shfl_xor(vmax, 32));
                float mnew = fmaxf(mrun[nt], vmax);
                alpha[nt] = __expf(mrun[nt] - mnew);
                mrun[nt] = mnew;
                float rsum = 0.f;
#pragma unroll
                for (int mt = 0; mt < 4; mt++)
#pragma unroll
                    for (int r = 0; r < 4; r++) {
                        float p = __expf(st[mt][nt][r] - mnew);
                        st[mt][nt][r] = p;
                        rsum += p;
                    }
                rsum += __shfl_xor(rsum, 16);
                rsum += __shfl_xor(rsum, 32);
                lrun[nt] = lrun[nt] * alpha[nt] + rsum;
                // P -> LDS (b64 packed writes, row=q col=key)
#pragma unroll
                for (int mt = 0; mt < 4; mt++) {
                    u32 p01 = pack2bf(st[mt][nt][0], st[mt][nt][1]);
                    u32 p23 = pack2bf(st[mt][nt][2], st[mt][nt][3]);
                    uint2 pk; pk.x = p01; pk.y = p23;
                    *(uint2*)(lP[wave] + (nt * 16 + l16) * LDP + mt * 16 + quad * 4) = pk;
                }
            }
            // rescale O by alpha (broadcast to C-layout rows)
#pragma unroll
            for (int mtq = 0; mtq < 2; mtq++)
#pragma unroll
                for (int r = 0; r < 4; r++) {
                    float av = __shfl(alpha[mtq], quad * 4 + r);
#pragma unroll
                    for (int ntd = 0; ntd < 8; ntd++) o[mtq][ntd][r] *= av;
                }
            // PV: O[q][d] += P[q][key] * V[key][d]
#pragma unroll
            for (int kfi = 0; kfi < 2; kfi++) {
                bf16x8 pf0 = *(const bf16x8*)(lP[wave] + l16 * LDP + kfi * 32 + quad * 8);
                bf16x8 pf1 = *(const bf16x8*)(lP[wave] + (16 + l16) * LDP + kfi * 32 + quad * 8);
#pragma unroll
                for (int ntd = 0; ntd < 8; ntd++) {
                    bf16x8 vfr = *(const bf16x8*)(lV[kfi] + (ntd * 16 + l16) * 32 + quad * 8);
                    o[0][ntd] = mfma16(pf0, vfr, o[0][ntd]);
                    o[1][ntd] = mfma16(pf1, vfr, o[1][ntd]);
                }
            }
        }
    }
    // epilogue: O /= l
#pragma unroll
    for (int mtq = 0; mtq < 2; mtq++) {
        float linv[4];
#pragma unroll
        for (int r = 0; r < 4; r++) linv[r] = 1.0f / __shfl(lrun[mtq], quad * 4 + r);
#pragma unroll
        for (int ntd = 0; ntd < 8; ntd++)
#pragma unroll
            for (int r = 0; r < 4; r++) {
                int q = qw + mtq * 16 + quad * 4 + r;
                Z[(size_t)(b * SEQ + q) * DMODEL + h * DHEAD + ntd * 16 + l16] =
                    f2bf(o[mtq][ntd][r] * linv[r]);
            }
    }
}

extern "C" void kernel_launch(void* const* d_in, const int* in_sizes, int n_in,
                              void* d_out, int out_size, void* d_ws, size_t ws_size,
                              hipStream_t stream) {
    const float* x    = (const float*)d_in[0];
    const float* fcos = (const float*)d_in[1];
    const float* fsin = (const float*)d_in[2];
    const float* wq   = (const float*)d_in[3];
    const float* wk   = (const float*)d_in[4];
    const float* wv   = (const float*)d_in[5];
    const float* wo   = (const float*)d_in[6];
    float* out = (float*)d_out;
    char* ws = (char*)d_ws;

    const size_t MiB = 1024ull * 1024ull;
    u16* xb    = (u16*)(ws);              // 32MiB [4096][4096]; reused as zb after QKV gemm
    u16* zb    = xb;
    u16* wqkvt = (u16*)(ws + 32 * MiB);   // 48MiB [6144][4096]
    u16* wot   = (u16*)(ws + 80 * MiB);   // 32MiB [4096][4096]
    u16* qkv   = (u16*)(ws + 112 * MiB);  // 48MiB [4096][6144]
    u16* vtb   = (u16*)(ws + 160 * MiB);  // 8MiB  [2][1024][2048]

    f2bf_kernel<<<16384, 256, 0, stream>>>(x, xb, TOKENS * DMODEL);
    dim3 tb(32, 8);
    transpose_kernel<<<dim3(128, 128), tb, 0, stream>>>(wq, wqkvt, 4096, 4096);
    transpose_kernel<<<dim3(32, 128), tb, 0, stream>>>(wk, wqkvt + (size_t)4096 * 4096, 4096, 1024);
    transpose_kernel<<<dim3(32, 128), tb, 0, stream>>>(wv, wqkvt + (size_t)5120 * 4096, 4096, 1024);
    transpose_kernel<<<dim3(128, 128), tb, 0, stream>>>(wo, wot, 4096, 4096);

    gemm256<false><<<dim3(24, 16), 512, 0, stream>>>(xb, wqkvt, qkv, 4096, QKVN, 4096);

    rope2_kernel<<<32768, 256, 0, stream>>>(qkv, fcos, fsin, NHEAD, 0, 0.08838834764831845f);
    rope2_kernel<<<8192, 256, 0, stream>>>(qkv, fcos, fsin, NKV, DMODEL, 1.0f);

    vtrans_kernel<<<dim3(32, 64, 2), tb, 0, stream>>>(qkv, vtb);

    flash2_kernel<<<dim3(16, 32, 2), 256, 0, stream>>>(qkv, vtb, zb);

    gemm256<true><<<dim3(16, 16), 512, 0, stream>>>(zb, wot, out, 4096, 4096, 4096);
}